// Round 1
// baseline (10.920 us; speedup 1.0000x reference)
//
#include <hip/hip_runtime.h>

// CrossGraphDA_15444702396481
//
// Algebraic identity: with x3n = 2*x3 - G and x4n = 2*x4 - G (identical G),
//   delta = x3n.mean(0) - x4n.mean(0) = 2*(mean(x3,0) - mean(x4,0))
// so the entire GNN pipeline (attention, top-k, SAGE, BN, conv) cancels.
// loss = dot(delta, delta) depends only on x3 (d_in[2]) and x4 (d_in[3]).

#define N_NODES 8192
#define NCOL 32
#define NBLK 64
#define ROWS_PER_BLK (N_NODES / NBLK)  // 128

__global__ void cgda_colsum_diff(const float* __restrict__ x3,
                                 const float* __restrict__ x4,
                                 float* __restrict__ partials) {
    // 256 threads: col = tid&31, row-group = tid>>5 (0..7)
    const int tid = threadIdx.x;
    const int col = tid & 31;
    const int rg  = tid >> 5;
    const int row_base = blockIdx.x * ROWS_PER_BLK;
    float acc = 0.f;
#pragma unroll
    for (int r = rg; r < ROWS_PER_BLK; r += 8) {
        const int i = (row_base + r) * NCOL + col;
        acc += x3[i] - x4[i];
    }
    __shared__ float s[8][32];
    s[rg][col] = acc;
    __syncthreads();
    if (tid < 32) {
        float t = 0.f;
#pragma unroll
        for (int g = 0; g < 8; ++g) t += s[g][tid];
        partials[blockIdx.x * 32 + tid] = t;
    }
}

__global__ void cgda_finish(const float* __restrict__ partials,
                            float* __restrict__ out) {
    const int lane = threadIdx.x;  // 64 threads, one wave
    float d = 0.f;
    if (lane < 32) {
        float sum = 0.f;
#pragma unroll
        for (int b = 0; b < NBLK; ++b) sum += partials[b * 32 + lane];
        const float delta = 2.0f * sum / (float)N_NODES;
        d = delta * delta;
    }
    // full-wave (64-lane) reduction; lanes >=32 contribute 0
#pragma unroll
    for (int off = 32; off > 0; off >>= 1) d += __shfl_down(d, off);
    if (lane == 0) out[0] = d;
}

extern "C" void kernel_launch(void* const* d_in, const int* in_sizes, int n_in,
                              void* d_out, int out_size, void* d_ws, size_t ws_size,
                              hipStream_t stream) {
    (void)in_sizes; (void)n_in; (void)out_size; (void)ws_size;
    const float* x3 = (const float*)d_in[2];
    const float* x4 = (const float*)d_in[3];
    float* partials = (float*)d_ws;  // NBLK*NCOL floats = 8 KiB, rewritten fully each call

    cgda_colsum_diff<<<NBLK, 256, 0, stream>>>(x3, x4, partials);
    cgda_finish<<<1, 64, 0, stream>>>(partials, (float*)d_out);
}